// Round 1
// baseline (371.148 us; speedup 1.0000x reference)
//
#include <hip/hip_runtime.h>
#include <hip/hip_bf16.h>
#include <math.h>

#define N_NODES   100000
#define N_EDGES   1600000
#define IN_FEAT   50
#define HIDDEN    64
#define N_CLASSES 41
#define NC48      48          // padded class width
#define N_TILES   (N_NODES / 16)   // 6250 exactly

#define N_WIN     8
#define WIN_SZ    ((N_NODES + N_WIN - 1) / N_WIN)   // 12500

#define SCAN_CHUNK 2048
#define SCAN_NBLK  ((N_NODES + SCAN_CHUNK - 1) / SCAN_CHUNK)   // 49 (<=64)

#define BUCKET_EPT 4
#define BUCKET_BLOCKS ((N_EDGES + 256 * BUCKET_EPT - 1) / (256 * BUCKET_EPT)) // 1563
#define BPW 800            // permuteB blocks per window (grid-stride robust)

typedef __attribute__((ext_vector_type(8))) _Float16 half8;
typedef __attribute__((ext_vector_type(4))) float   float4v;

union f16pk { _Float16 h[2]; unsigned u; };
union quadpk { uint4 v; _Float16 h[8]; };

// index clamp: any value outside [0,N_NODES) becomes 0 (defensive; see R11)
__device__ __forceinline__ int clampidx(int i) {
  return ((unsigned)i < (unsigned)N_NODES) ? i : 0;
}

// ---------------------------------------------------------------------------
// Zero the per-node counters.
// ---------------------------------------------------------------------------
__global__ __launch_bounds__(256) void zeroc_kernel(int* __restrict__ counts) {
  int i = blockIdx.x * 256 + threadIdx.x;
  if (i < N_NODES) counts[i] = 0;
}

// ---------------------------------------------------------------------------
// Prep A: x (f32 [N][50]) -> xh (f16 [N][64], k-padded with zeros)
// ---------------------------------------------------------------------------
__global__ __launch_bounds__(256) void packx_kernel(
    const float* __restrict__ x, _Float16* __restrict__ xh) {
  int i = blockIdx.x * 256 + threadIdx.x;
  if (i >= N_NODES * 64) return;
  int node = i >> 6, c = i & 63;
  xh[i] = (c < IN_FEAT) ? (_Float16)x[node * IN_FEAT + c] : (_Float16)0.f;
}

// ---------------------------------------------------------------------------
// Prep B: pack transposed f16-pair weights for MFMA B-fragments.
// ---------------------------------------------------------------------------
__global__ __launch_bounds__(256) void packwts_kernel(
    const float* __restrict__ W1l, const float* __restrict__ W1r,
    const float* __restrict__ W2l, const float* __restrict__ W2r,
    unsigned* __restrict__ wt1l, unsigned* __restrict__ wt1r,
    unsigned* __restrict__ wt2l, unsigned* __restrict__ wt2r) {
  int i = blockIdx.x * 256 + threadIdx.x;
  f16pk pk;
  if (i < 2048 * 2) {                       // layer-1 weights
    int which = i >> 11, j = i & 2047;
    int n = j >> 5, kp = j & 31;
    const float* W = which ? W1r : W1l;
    int k0 = 2 * kp, k1 = 2 * kp + 1;
    pk.h[0] = (_Float16)((k0 < IN_FEAT) ? W[k0 * HIDDEN + n] : 0.f);
    pk.h[1] = (_Float16)((k1 < IN_FEAT) ? W[k1 * HIDDEN + n] : 0.f);
    (which ? wt1r : wt1l)[j] = pk.u;
  } else if (i < 4096 + 2 * 1536) {         // layer-2 weights
    int j = i - 4096;
    int which = (j >= 1536), jj = which ? j - 1536 : j;
    int n = jj >> 5, kp = jj & 31;
    const float* W = which ? W2r : W2l;
    pk.h[0] = (_Float16)((n < N_CLASSES) ? W[(2 * kp) * N_CLASSES + n] : 0.f);
    pk.h[1] = (_Float16)((n < N_CLASSES) ? W[(2 * kp + 1) * N_CLASSES + n] : 0.f);
    (which ? wt2r : wt2l)[jj] = pk.u;
  }
}

// ---------------------------------------------------------------------------
// Counting-sort by dst.  Step 1: histogram of dst.
// ---------------------------------------------------------------------------
__global__ __launch_bounds__(256) void hist_kernel(
    const int* __restrict__ dst, int* __restrict__ counts) {
  int e = blockIdx.x * 256 + threadIdx.x;
  if (e < N_EDGES) atomicAdd(&counts[dst[e]], 1);
}

// Step 2a: per-chunk (2048 counts) reduction -> partial[49]
__global__ __launch_bounds__(256) void scanA_kernel(
    const int* __restrict__ counts, int* __restrict__ partial) {
  __shared__ int lds[256];
  int base = blockIdx.x * SCAN_CHUNK;
  int sum = 0;
  for (int i = threadIdx.x; i < SCAN_CHUNK; i += 256) {
    int idx = base + i;
    sum += (idx < N_NODES) ? counts[idx] : 0;
  }
  lds[threadIdx.x] = sum;
  __syncthreads();
  for (int off = 128; off >= 1; off >>= 1) {
    if (threadIdx.x < off) lds[threadIdx.x] += lds[threadIdx.x + off];
    __syncthreads();
  }
  if (threadIdx.x == 0) partial[blockIdx.x] = lds[0];
}

// Step 2b: single-wave exclusive scan of the 49 partials (in place).
__global__ __launch_bounds__(64) void scanB_kernel(
    int* __restrict__ partial, int* __restrict__ start) {
  int lane = threadIdx.x;
  int orig = (lane < SCAN_NBLK) ? partial[lane] : 0;
  int v = orig;
  for (int off = 1; off < 64; off <<= 1) {
    int t = __shfl_up(v, off);
    if (lane >= off) v += t;
  }
  if (lane < SCAN_NBLK) partial[lane] = v - orig;   // exclusive
  if (lane == 0) start[N_NODES] = N_EDGES;
}

// Step 2c: per-chunk exclusive scan + chunk offset -> start[], cursor[], and
// the 8 window bucket bases (wcur[w] = start[w*WIN_SZ]).
__global__ __launch_bounds__(256) void scanC_kernel(
    const int* __restrict__ counts, const int* __restrict__ blockoff,
    int* __restrict__ start, int* __restrict__ cursor,
    int* __restrict__ wcur) {
  __shared__ int lds[256];
  const int PT = SCAN_CHUNK / 256;                  // 8
  int base = blockIdx.x * SCAN_CHUNK + threadIdx.x * PT;
  int c[PT];
  int tsum = 0;
#pragma unroll
  for (int k = 0; k < PT; ++k) {
    int idx = base + k;
    c[k] = (idx < N_NODES) ? counts[idx] : 0;
    tsum += c[k];
  }
  lds[threadIdx.x] = tsum;
  __syncthreads();
  for (int off = 1; off < 256; off <<= 1) {         // Hillis-Steele inclusive
    int t = (threadIdx.x >= (unsigned)off) ? lds[threadIdx.x - off] : 0;
    __syncthreads();
    lds[threadIdx.x] += t;
    __syncthreads();
  }
  int run = blockoff[blockIdx.x] + lds[threadIdx.x] - tsum;  // exclusive
#pragma unroll
  for (int k = 0; k < PT; ++k) {
    int idx = base + k;
    if (idx < N_NODES) {
      start[idx] = run; cursor[idx] = run;
      if (idx % WIN_SZ == 0) wcur[idx / WIN_SZ] = run;  // bucket base
    }
    run += c[k];
  }
}

// ---------------------------------------------------------------------------
// R14 phase A: single-pass bucket of (src,dst) pairs into 8 window regions.
// Exact, disjoint regions: window w's bucket is pairs[start[w*WIN_SZ] ..
// start[(w+1)*WIN_SZ]) (bases preloaded into wcur by scanC).  Per-block LDS
// ranking -> one global atomic per window per block -> ~1KB grouped writes.
// Replaces permute8's 8 passes over dst (51 MB fetch + 73 MB amplified write).
// ---------------------------------------------------------------------------
__global__ __launch_bounds__(256) void bucket_kernel(
    const int* __restrict__ src, const int* __restrict__ dst,
    int* __restrict__ wcur, int2* __restrict__ pairs) {
  __shared__ int lcnt[N_WIN];
  __shared__ int lbase[N_WIN];
  int tid = threadIdx.x;
  if (tid < N_WIN) lcnt[tid] = 0;
  __syncthreads();
  int base = blockIdx.x * (256 * BUCKET_EPT);
  int e[BUCKET_EPT], s[BUCKET_EPT], d[BUCKET_EPT], w[BUCKET_EPT], rk[BUCKET_EPT];
#pragma unroll
  for (int k = 0; k < BUCKET_EPT; ++k) {
    e[k] = base + k * 256 + tid;
    if (e[k] < N_EDGES) {
      s[k] = src[e[k]];
      d[k] = dst[e[k]];
      w[k] = (unsigned)d[k] / (unsigned)WIN_SZ;
      rk[k] = atomicAdd(&lcnt[w[k]], 1);
    }
  }
  __syncthreads();
  if (tid < N_WIN) lbase[tid] = atomicAdd(&wcur[tid], lcnt[tid]);
  __syncthreads();
#pragma unroll
  for (int k = 0; k < BUCKET_EPT; ++k) {
    if (e[k] < N_EDGES) {
      int2 p; p.x = s[k]; p.y = d[k];
      pairs[lbase[w[k]] + rk[k]] = p;
    }
  }
}

// ---------------------------------------------------------------------------
// R14 phase B: window-local permute.  XCD-affine (win = blockIdx & 7) so each
// window's pair stream (1.6 MB), cursor slice (50 KB) and dirty ssrc region
// (800 KB) all stay resident in one XCD's 4 MB L2 -> dirty lines written back
// once instead of ~11x.  Grid-stride over the bucket for skew robustness.
// ---------------------------------------------------------------------------
__global__ __launch_bounds__(256) void permuteB_kernel(
    const int2* __restrict__ pairs, const int* __restrict__ start,
    int* __restrict__ cursor, int* __restrict__ sorted_src) {
  int win  = blockIdx.x & 7;
  int rank = blockIdx.x >> 3;
  int lo = start[win * WIN_SZ];
  int hi = start[(win + 1) * WIN_SZ];   // start[N_NODES] == N_EDGES for win=7
  for (int i = lo + rank * 256 + (int)threadIdx.x; i < hi; i += BPW * 256) {
    int2 p = pairs[i];
    int pos = atomicAdd(&cursor[p.y], 1);
    sorted_src[pos] = p.x;
  }
}

// ---------------------------------------------------------------------------
// Fused gather1 + MLP: one block per 16-node tile (6250 blocks).
// Waves 0-3 each gather 4 nodes (R13 dwordx4 pattern) -> agg rows in f32 LDS
// (no aggh global round-trip, no intermediate f16 quantization).
// Barrier; wave 0 runs the MFMA MLP for the tile:
//   h  = relu(agg@W1l + x@W1r + b1)   (LDS only)
//   hl = h@W2l            -> hlh   [N][48] f16
//   op = h@W2r + b2       -> opart [N][48] f32
// ---------------------------------------------------------------------------
__global__ __launch_bounds__(256) void g1mlp_kernel(
    const uint4* __restrict__ xq,          // xh as quads [N][8]
    const int* __restrict__ start, const int* __restrict__ ssrc,
    const _Float16* __restrict__ xh,
    const unsigned* __restrict__ wt1l, const unsigned* __restrict__ wt1r,
    const unsigned* __restrict__ wt2l, const unsigned* __restrict__ wt2r,
    const float* __restrict__ b1, const float* __restrict__ b2,
    _Float16* __restrict__ hlh, float* __restrict__ opart) {
  __shared__ float aggF[16][64];    // 4 KB: f32 agg rows for the tile
  __shared__ float sH[16][68];      // 4.25 KB: h round-trip (padded)
  int tile = blockIdx.x;
  int wv = threadIdx.x >> 6;        // wave 0..3
  int lane = threadIdx.x & 63;
  int r = lane >> 3, q = lane & 7;

  // ---- gather phase: wave wv handles nodes tile*16 + wv*4 .. +4 ----
  for (int k = 0; k < 4; ++k) {
    int node = tile * 16 + wv * 4 + k;

    float accA[8] = {0.f, 0.f, 0.f, 0.f, 0.f, 0.f, 0.f, 0.f};
    float accB[8] = {0.f, 0.f, 0.f, 0.f, 0.f, 0.f, 0.f, 0.f};

    int s0 = start[node], s1 = start[node + 1];
    for (int base = s0; base < s1; base += 64) {
      int cnt = s1 - base;
      if (cnt > 64) cnt = 64;
      int idxv = (lane < cnt) ? ssrc[base + lane] : 0;
      int j = 0;
      for (; j + 16 <= cnt; j += 16) {
        int iA = clampidx(__shfl(idxv, j + r));
        int iB = clampidx(__shfl(idxv, j + 8 + r));
        quadpk uA, uB;
        uA.v = xq[iA * 8 + q];
        uB.v = xq[iB * 8 + q];
#pragma unroll
        for (int t = 0; t < 8; ++t) {
          accA[t] += (float)uA.h[t];
          accB[t] += (float)uB.h[t];
        }
      }
      for (; j + 8 <= cnt; j += 8) {
        int iA = clampidx(__shfl(idxv, j + r));
        quadpk uA;
        uA.v = xq[iA * 8 + q];
#pragma unroll
        for (int t = 0; t < 8; ++t) accA[t] += (float)uA.h[t];
      }
      if (j < cnt) {
        int nrem = cnt - j;
        int iA = clampidx(__shfl(idxv, j + r));
        if (r < nrem) {
          quadpk uA;
          uA.v = xq[iA * 8 + q];
#pragma unroll
          for (int t = 0; t < 8; ++t) accA[t] += (float)uA.h[t];
        }
      }
    }
#pragma unroll
    for (int t = 0; t < 8; ++t) accA[t] += accB[t];
#pragma unroll
    for (int off = 8; off <= 32; off <<= 1) {
#pragma unroll
      for (int t = 0; t < 8; ++t) accA[t] += __shfl_xor(accA[t], off);
    }
    if (r == 0) {
      int nl = wv * 4 + k;
#pragma unroll
      for (int t = 0; t < 8; ++t) aggF[nl][q * 8 + t] = accA[t];
    }
  }
  __syncthreads();

  // ---- MLP phase: wave 0 only ----
  if (wv != 0) return;
  int m = lane & 15, quad = lane >> 4;

  half8 Aa[2], Ax[2];
#pragma unroll
  for (int s = 0; s < 2; ++s) {
    const float* pa = &aggF[m][s * 32 + quad * 8];
    half8 A;
#pragma unroll
    for (int jj = 0; jj < 8; ++jj) A[jj] = (_Float16)pa[jj];
    Aa[s] = A;
    Ax[s] = *(const half8*)(xh + (tile * 16 + m) * 64 + s * 32 + quad * 8);
  }

#pragma unroll
  for (int t = 0; t < 4; ++t) {
    int n = t * 16 + m;
    half8 Bl0 = *(const half8*)(wt1l + n * 32 + quad * 4);
    half8 Bl1 = *(const half8*)(wt1l + n * 32 + 16 + quad * 4);
    half8 Br0 = *(const half8*)(wt1r + n * 32 + quad * 4);
    half8 Br1 = *(const half8*)(wt1r + n * 32 + 16 + quad * 4);
    float4v acc = {0.f, 0.f, 0.f, 0.f};
    acc = __builtin_amdgcn_mfma_f32_16x16x32_f16(Aa[0], Bl0, acc, 0, 0, 0);
    acc = __builtin_amdgcn_mfma_f32_16x16x32_f16(Aa[1], Bl1, acc, 0, 0, 0);
    acc = __builtin_amdgcn_mfma_f32_16x16x32_f16(Ax[0], Br0, acc, 0, 0, 0);
    acc = __builtin_amdgcn_mfma_f32_16x16x32_f16(Ax[1], Br1, acc, 0, 0, 0);
    float bv = b1[n];
#pragma unroll
    for (int rr = 0; rr < 4; ++rr) {
      sH[quad * 4 + rr][n] = fmaxf(acc[rr] + bv, 0.f);
    }
  }

  half8 Ah[2];
#pragma unroll
  for (int s = 0; s < 2; ++s) {
    const float* pr = &sH[m][s * 32 + quad * 8];
    half8 A;
#pragma unroll
    for (int jj = 0; jj < 8; ++jj) A[jj] = (_Float16)pr[jj];
    Ah[s] = A;
  }

#pragma unroll
  for (int t = 0; t < 3; ++t) {
    int n = t * 16 + m;
    half8 Cl0 = *(const half8*)(wt2l + n * 32 + quad * 4);
    half8 Cl1 = *(const half8*)(wt2l + n * 32 + 16 + quad * 4);
    half8 Cr0 = *(const half8*)(wt2r + n * 32 + quad * 4);
    half8 Cr1 = *(const half8*)(wt2r + n * 32 + 16 + quad * 4);
    float4v acc2 = {0.f, 0.f, 0.f, 0.f};
    float4v acc3 = {0.f, 0.f, 0.f, 0.f};
    acc2 = __builtin_amdgcn_mfma_f32_16x16x32_f16(Ah[0], Cl0, acc2, 0, 0, 0);
    acc2 = __builtin_amdgcn_mfma_f32_16x16x32_f16(Ah[1], Cl1, acc2, 0, 0, 0);
    acc3 = __builtin_amdgcn_mfma_f32_16x16x32_f16(Ah[0], Cr0, acc3, 0, 0, 0);
    acc3 = __builtin_amdgcn_mfma_f32_16x16x32_f16(Ah[1], Cr1, acc3, 0, 0, 0);
    float bv = (n < N_CLASSES) ? b2[n] : 0.f;
#pragma unroll
    for (int rr = 0; rr < 4; ++rr) {
      int row = tile * 16 + quad * 4 + rr;
      hlh[row * NC48 + n] = (_Float16)acc2[rr];
      opart[row * NC48 + n] = acc3[rr] + bv;
    }
  }
}

// ---------------------------------------------------------------------------
// Gather 2 v3 (dwordx4) + softmax: hl rows = 6 quads (96 B).  Lanes with
// q<6 load; butterfly reduce; lanes (r==0, q<6) each own classes q*8..q*8+7.
// ---------------------------------------------------------------------------
__global__ __launch_bounds__(256) void gather2_kernel(
    const uint4* __restrict__ hq,          // hlh as quads [N][6]
    const float4* __restrict__ opart4,     // opart as float4 [N][12]
    const int* __restrict__ start, const int* __restrict__ ssrc,
    float* __restrict__ out) {
  int node = (blockIdx.x * 256 + threadIdx.x) >> 6;
  if (node >= N_NODES) return;
  int lane = threadIdx.x & 63;
  int r = lane >> 3, q = lane & 7;
  bool qOK = (q < 6);

  // own opart features (issued early)
  float op[8] = {0.f, 0.f, 0.f, 0.f, 0.f, 0.f, 0.f, 0.f};
  if (r == 0 && qOK) {
    float4 a = opart4[node * 12 + q * 2];
    float4 b = opart4[node * 12 + q * 2 + 1];
    op[0] = a.x; op[1] = a.y; op[2] = a.z; op[3] = a.w;
    op[4] = b.x; op[5] = b.y; op[6] = b.z; op[7] = b.w;
  }

  float accA[8] = {0.f, 0.f, 0.f, 0.f, 0.f, 0.f, 0.f, 0.f};
  float accB[8] = {0.f, 0.f, 0.f, 0.f, 0.f, 0.f, 0.f, 0.f};

  int s0 = start[node], s1 = start[node + 1];
  for (int base = s0; base < s1; base += 64) {
    int cnt = s1 - base;
    if (cnt > 64) cnt = 64;
    int idxv = (lane < cnt) ? ssrc[base + lane] : 0;
    int j = 0;
    for (; j + 16 <= cnt; j += 16) {
      int iA = clampidx(__shfl(idxv, j + r));
      int iB = clampidx(__shfl(idxv, j + 8 + r));
      if (qOK) {
        quadpk uA, uB;
        uA.v = hq[iA * 6 + q];
        uB.v = hq[iB * 6 + q];
#pragma unroll
        for (int t = 0; t < 8; ++t) {
          accA[t] += (float)uA.h[t];
          accB[t] += (float)uB.h[t];
        }
      }
    }
    for (; j + 8 <= cnt; j += 8) {
      int iA = clampidx(__shfl(idxv, j + r));
      if (qOK) {
        quadpk uA;
        uA.v = hq[iA * 6 + q];
#pragma unroll
        for (int t = 0; t < 8; ++t) accA[t] += (float)uA.h[t];
      }
    }
    if (j < cnt) {
      int nrem = cnt - j;
      int iA = clampidx(__shfl(idxv, j + r));
      if (r < nrem && qOK) {
        quadpk uA;
        uA.v = hq[iA * 6 + q];
#pragma unroll
        for (int t = 0; t < 8; ++t) accA[t] += (float)uA.h[t];
      }
    }
  }
#pragma unroll
  for (int t = 0; t < 8; ++t) accA[t] += accB[t];
#pragma unroll
  for (int off = 8; off <= 32; off <<= 1) {
#pragma unroll
    for (int t = 0; t < 8; ++t) accA[t] += __shfl_xor(accA[t], off);
  }

  // lanes (r==0, q<6): o[t] = opart + agg for class f = q*8+t (valid f<41)
  bool own = (r == 0) && qOK;
  float o[8];
  float lmax = -INFINITY;
#pragma unroll
  for (int t = 0; t < 8; ++t) {
    int f = q * 8 + t;
    o[t] = op[t] + accA[t];
    if (own && f < N_CLASSES) lmax = fmaxf(lmax, o[t]);
  }
  float vm = own ? lmax : -INFINITY;
#pragma unroll
  for (int off = 32; off >= 1; off >>= 1) vm = fmaxf(vm, __shfl_xor(vm, off));
  float lsum = 0.f;
#pragma unroll
  for (int t = 0; t < 8; ++t) {
    int f = q * 8 + t;
    if (own && f < N_CLASSES) lsum += expf(o[t] - vm);
  }
#pragma unroll
  for (int off = 32; off >= 1; off >>= 1) lsum += __shfl_xor(lsum, off);
  float lse = logf(lsum);
  if (own) {
#pragma unroll
    for (int t = 0; t < 8; ++t) {
      int f = q * 8 + t;
      if (f < N_CLASSES) out[node * N_CLASSES + f] = o[t] - vm - lse;
    }
  }
}

// ---------------------------------------------------------------------------
extern "C" void kernel_launch(void* const* d_in, const int* in_sizes, int n_in,
                              void* d_out, int out_size, void* d_ws, size_t ws_size,
                              hipStream_t stream) {
  const float* x   = (const float*)d_in[0];
  const float* W1l = (const float*)d_in[1];
  const float* W1r = (const float*)d_in[2];
  const float* b1  = (const float*)d_in[3];
  const float* W2l = (const float*)d_in[4];
  const float* W2r = (const float*)d_in[5];
  const float* b2  = (const float*)d_in[6];
  const int*   src = (const int*)d_in[7];
  const int*   dst = (const int*)d_in[8];
  float* out = (float*)d_out;

  int* counts  = (int*)d_ws;
  int* start   = counts + N_NODES;
  int* cursor  = start + (N_NODES + 1);
  int* partial = cursor + N_NODES;
  int* wcur    = partial + 56;          // 8 ints, tail of the partial[64] slot
  int* ssrc    = partial + 64;
  unsigned* wt1l = (unsigned*)(ssrc + N_EDGES);
  unsigned* wt1r = wt1l + 2048;
  unsigned* wt2l = wt1r + 2048;
  unsigned* wt2r = wt2l + 1536;
  // 256-B align opart so all downstream quad accesses are naturally aligned
  uintptr_t pal = ((uintptr_t)(wt2r + 1536) + 255) & ~(uintptr_t)255;
  float* opart   = (float*)pal;
  _Float16* xh   = (_Float16*)(opart + (size_t)N_NODES * NC48);
  _Float16* hlh  = xh + (size_t)N_NODES * 64;

  // pairs (12.8 MB) aliases opart (19.2 MB): fully consumed by permuteB
  // before g1mlp produces opart.  Stream order guarantees no overlap in time.
  int2* pairs = (int2*)opart;

  int eblocks = (N_EDGES + 255) / 256;   // 6250

  zeroc_kernel<<<(N_NODES + 255) / 256, 256, 0, stream>>>(counts);
  packx_kernel<<<(N_NODES * 64 + 255) / 256, 256, 0, stream>>>(x, xh);
  packwts_kernel<<<(7168 + 255) / 256, 256, 0, stream>>>(
      W1l, W1r, W2l, W2r, wt1l, wt1r, wt2l, wt2r);
  hist_kernel<<<eblocks, 256, 0, stream>>>(dst, counts);
  scanA_kernel<<<SCAN_NBLK, 256, 0, stream>>>(counts, partial);
  scanB_kernel<<<1, 64, 0, stream>>>(partial, start);
  scanC_kernel<<<SCAN_NBLK, 256, 0, stream>>>(counts, partial, start, cursor, wcur);
  bucket_kernel<<<BUCKET_BLOCKS, 256, 0, stream>>>(src, dst, wcur, pairs);
  permuteB_kernel<<<N_WIN * BPW, 256, 0, stream>>>(pairs, start, cursor, ssrc);

  g1mlp_kernel<<<N_TILES, 256, 0, stream>>>(
      (const uint4*)xh, start, ssrc, xh, wt1l, wt1r, wt2l, wt2r,
      b1, b2, hlh, opart);

  int gblocks = (N_NODES * 64 + 255) / 256;   // one wave per node
  gather2_kernel<<<gblocks, 256, 0, stream>>>(
      (const uint4*)hlh, (const float4*)opart, start, ssrc, out);
}

// Round 4
// 311.535 us; speedup vs baseline: 1.1914x; 1.1914x over previous
//
#include <hip/hip_runtime.h>
#include <hip/hip_bf16.h>
#include <math.h>

#define N_NODES   100000
#define N_EDGES   1600000
#define IN_FEAT   50
#define HIDDEN    64
#define N_CLASSES 41
#define NC48      48          // padded class width
#define N_TILES   (N_NODES / 16)   // 6250 exactly

#define SCAN_CHUNK 2048
#define SCAN_NBLK  ((N_NODES + SCAN_CHUNK - 1) / SCAN_CHUNK)   // 49 (<=64)

// R15-17: bucketed counting sort
#define NPB   200                      // nodes per bucket
#define NBUK  (N_NODES / NPB)          // 500 buckets exactly
#define BEPT  16                       // edges per thread in bucketA
#define BA_BLOCKS ((N_EDGES + 256 * BEPT - 1) / (256 * BEPT))  // 391
#define SCAP  4096                     // sort2 LDS staging capacity (edges)

typedef __attribute__((ext_vector_type(8))) _Float16 half8;
typedef __attribute__((ext_vector_type(4))) float   float4v;

union f16pk { _Float16 h[2]; unsigned u; };
union quadpk { uint4 v; _Float16 h[8]; };

// index clamp: any value outside [0,N_NODES) becomes 0 (defensive; see R11)
__device__ __forceinline__ int clampidx(int i) {
  return ((unsigned)i < (unsigned)N_NODES) ? i : 0;
}

// ---------------------------------------------------------------------------
// Zero the per-node counters.
// ---------------------------------------------------------------------------
__global__ __launch_bounds__(256) void zeroc_kernel(int* __restrict__ counts) {
  int i = blockIdx.x * 256 + threadIdx.x;
  if (i < N_NODES) counts[i] = 0;
}

// ---------------------------------------------------------------------------
// Prep A: x (f32 [N][50]) -> xh (f16 [N][64], k-padded with zeros)
// ---------------------------------------------------------------------------
__global__ __launch_bounds__(256) void packx_kernel(
    const float* __restrict__ x, _Float16* __restrict__ xh) {
  int i = blockIdx.x * 256 + threadIdx.x;
  if (i >= N_NODES * 64) return;
  int node = i >> 6, c = i & 63;
  xh[i] = (c < IN_FEAT) ? (_Float16)x[node * IN_FEAT + c] : (_Float16)0.f;
}

// ---------------------------------------------------------------------------
// Prep B: pack transposed f16-pair weights for MFMA B-fragments.
// ---------------------------------------------------------------------------
__global__ __launch_bounds__(256) void packwts_kernel(
    const float* __restrict__ W1l, const float* __restrict__ W1r,
    const float* __restrict__ W2l, const float* __restrict__ W2r,
    unsigned* __restrict__ wt1l, unsigned* __restrict__ wt1r,
    unsigned* __restrict__ wt2l, unsigned* __restrict__ wt2r) {
  int i = blockIdx.x * 256 + threadIdx.x;
  f16pk pk;
  if (i < 2048 * 2) {                       // layer-1 weights
    int which = i >> 11, j = i & 2047;
    int n = j >> 5, kp = j & 31;
    const float* W = which ? W1r : W1l;
    int k0 = 2 * kp, k1 = 2 * kp + 1;
    pk.h[0] = (_Float16)((k0 < IN_FEAT) ? W[k0 * HIDDEN + n] : 0.f);
    pk.h[1] = (_Float16)((k1 < IN_FEAT) ? W[k1 * HIDDEN + n] : 0.f);
    (which ? wt1r : wt1l)[j] = pk.u;
  } else if (i < 4096 + 2 * 1536) {         // layer-2 weights
    int j = i - 4096;
    int which = (j >= 1536), jj = which ? j - 1536 : j;
    int n = jj >> 5, kp = jj & 31;
    const float* W = which ? W2r : W2l;
    pk.h[0] = (_Float16)((n < N_CLASSES) ? W[(2 * kp) * N_CLASSES + n] : 0.f);
    pk.h[1] = (_Float16)((n < N_CLASSES) ? W[(2 * kp + 1) * N_CLASSES + n] : 0.f);
    (which ? wt2r : wt2l)[jj] = pk.u;
  }
}

// ---------------------------------------------------------------------------
// Counting-sort by dst.  Step 1: histogram of dst.
// ---------------------------------------------------------------------------
__global__ __launch_bounds__(256) void hist_kernel(
    const int* __restrict__ dst, int* __restrict__ counts) {
  int e = blockIdx.x * 256 + threadIdx.x;
  if (e < N_EDGES) atomicAdd(&counts[clampidx(dst[e])], 1);
}

// Step 2a: per-chunk (2048 counts) reduction -> partial[49]
__global__ __launch_bounds__(256) void scanA_kernel(
    const int* __restrict__ counts, int* __restrict__ partial) {
  __shared__ int lds[256];
  int base = blockIdx.x * SCAN_CHUNK;
  int sum = 0;
  for (int i = threadIdx.x; i < SCAN_CHUNK; i += 256) {
    int idx = base + i;
    sum += (idx < N_NODES) ? counts[idx] : 0;
  }
  lds[threadIdx.x] = sum;
  __syncthreads();
  for (int off = 128; off >= 1; off >>= 1) {
    if (threadIdx.x < off) lds[threadIdx.x] += lds[threadIdx.x + off];
    __syncthreads();
  }
  if (threadIdx.x == 0) partial[blockIdx.x] = lds[0];
}

// Step 2b: single-wave exclusive scan of the 49 partials (in place).
__global__ __launch_bounds__(64) void scanB_kernel(
    int* __restrict__ partial, int* __restrict__ start) {
  int lane = threadIdx.x;
  int orig = (lane < SCAN_NBLK) ? partial[lane] : 0;
  int v = orig;
  for (int off = 1; off < 64; off <<= 1) {
    int t = __shfl_up(v, off);
    if (lane >= off) v += t;
  }
  if (lane < SCAN_NBLK) partial[lane] = v - orig;   // exclusive
  if (lane == 0) start[N_NODES] = N_EDGES;
}

// Step 2c: per-chunk exclusive scan + chunk offset -> start[], cursor[], and
// the 500 bucket bases (wcur[b] = start[b*NPB]).
__global__ __launch_bounds__(256) void scanC_kernel(
    const int* __restrict__ counts, const int* __restrict__ blockoff,
    int* __restrict__ start, int* __restrict__ cursor,
    int* __restrict__ wcur) {
  __shared__ int lds[256];
  const int PT = SCAN_CHUNK / 256;                  // 8
  int base = blockIdx.x * SCAN_CHUNK + threadIdx.x * PT;
  int c[PT];
  int tsum = 0;
#pragma unroll
  for (int k = 0; k < PT; ++k) {
    int idx = base + k;
    c[k] = (idx < N_NODES) ? counts[idx] : 0;
    tsum += c[k];
  }
  lds[threadIdx.x] = tsum;
  __syncthreads();
  for (int off = 1; off < 256; off <<= 1) {         // Hillis-Steele inclusive
    int t = (threadIdx.x >= (unsigned)off) ? lds[threadIdx.x - off] : 0;
    __syncthreads();
    lds[threadIdx.x] += t;
    __syncthreads();
  }
  int run = blockoff[blockIdx.x] + lds[threadIdx.x] - tsum;  // exclusive
#pragma unroll
  for (int k = 0; k < PT; ++k) {
    int idx = base + k;
    if (idx < N_NODES) {
      start[idx] = run; cursor[idx] = run;
      if (idx % NPB == 0) wcur[idx / NPB] = run;    // bucket base
    }
    run += c[k];
  }
}

// ---------------------------------------------------------------------------
// R15 phase A (hardened): single pass over (src,dst); LDS-rank edges into 500
// buckets of NPB=200 nodes; regions pairs[start[b*NPB]..start[(b+1)*NPB]).
// Every scatter index is unsigned-clamped so no state corruption can fault.
// ---------------------------------------------------------------------------
__global__ __launch_bounds__(256) void bucketA_kernel(
    const int* __restrict__ src, const int* __restrict__ dst,
    int* __restrict__ wcur, int2* __restrict__ pairs) {
  __shared__ int lcnt[NBUK];
  __shared__ int lbase[NBUK];
  int tid = threadIdx.x;
  for (int i = tid; i < NBUK; i += 256) lcnt[i] = 0;
  __syncthreads();
  int base = blockIdx.x * (256 * BEPT);
  int s[BEPT], d[BEPT], rk[BEPT];
#pragma unroll
  for (int k = 0; k < BEPT; ++k) {
    int e = base + k * 256 + tid;
    rk[k] = -1;
    if (e < N_EDGES) {
      s[k] = src[e];
      d[k] = clampidx(dst[e]);
      int w = (unsigned)d[k] / (unsigned)NPB;       // < NBUK by construction
      rk[k] = atomicAdd(&lcnt[w], 1);
    }
  }
  __syncthreads();
  for (int i = tid; i < NBUK; i += 256)
    lbase[i] = atomicAdd(&wcur[i], lcnt[i]);
  __syncthreads();
#pragma unroll
  for (int k = 0; k < BEPT; ++k) {
    if (rk[k] >= 0) {
      int w = (unsigned)d[k] / (unsigned)NPB;
      int pos = lbase[w] + rk[k];
      if ((unsigned)pos < (unsigned)N_EDGES) {      // defensive: cannot fault
        int2 p; p.x = s[k]; p.y = d[k];
        pairs[pos] = p;
      }
    }
  }
}

// ---------------------------------------------------------------------------
// R15 phase B (hardened): per-bucket LDS counting sort.  One block per bucket
// (~3200 edges).  Per-node cursors in LDS, scatter src into a 16KB LDS
// staging buffer, stream the sorted segment out with contiguous coalesced
// stores.  All LDS/global scatter indices unsigned-clamped.  Skew fallback
// (> SCAP edges) does a bounded global scatter.
// ---------------------------------------------------------------------------
__global__ __launch_bounds__(256) void sort2_kernel(
    const int2* __restrict__ pairs, const int* __restrict__ start,
    int* __restrict__ cursor, int* __restrict__ ssrc) {
  __shared__ int obuf[SCAP];
  __shared__ int lcur[NPB];
  int b = blockIdx.x;
  int nbase = b * NPB;
  int lo = start[nbase];
  int hi = start[nbase + NPB];       // start[N_NODES] == N_EDGES for b=499
  int ne = hi - lo;
  int tid = threadIdx.x;
  if (ne >= 0 && ne <= SCAP) {
    for (int i = tid; i < NPB; i += 256) lcur[i] = start[nbase + i] - lo;
    __syncthreads();
    for (int i = lo + tid; i < hi; i += 256) {
      int2 p = pairs[i];
      unsigned li = (unsigned)(p.y - nbase);
      if (li < (unsigned)NPB) {                     // defensive
        int pos = atomicAdd(&lcur[li], 1);          // LDS atomic
        if ((unsigned)pos < (unsigned)SCAP) obuf[pos] = p.x;
      }
    }
    __syncthreads();
    for (int i = tid; i < ne; i += 256) ssrc[lo + i] = obuf[i];
  } else {
    // skew fallback: global scatter (slow but correct), bounded
    for (int i = lo + tid; i < hi; i += 256) {
      int2 p = pairs[i];
      int pos = atomicAdd(&cursor[clampidx(p.y)], 1);
      if ((unsigned)pos < (unsigned)N_EDGES) ssrc[pos] = p.x;
    }
  }
}

// ---------------------------------------------------------------------------
// Fused gather1 + MLP: one block per 16-node tile (6250 blocks).
// Waves 0-3 each gather 4 nodes (R13 dwordx4 pattern) -> agg rows in f32 LDS
// (no aggh global round-trip, no intermediate f16 quantization).
// Barrier; wave 0 runs the MFMA MLP for the tile:
//   h  = relu(agg@W1l + x@W1r + b1)   (LDS only)
//   hl = h@W2l            -> hlh   [N][48] f16
//   op = h@W2r + b2       -> opart [N][48] f32
// ---------------------------------------------------------------------------
__global__ __launch_bounds__(256) void g1mlp_kernel(
    const uint4* __restrict__ xq,          // xh as quads [N][8]
    const int* __restrict__ start, const int* __restrict__ ssrc,
    const _Float16* __restrict__ xh,
    const unsigned* __restrict__ wt1l, const unsigned* __restrict__ wt1r,
    const unsigned* __restrict__ wt2l, const unsigned* __restrict__ wt2r,
    const float* __restrict__ b1, const float* __restrict__ b2,
    _Float16* __restrict__ hlh, float* __restrict__ opart) {
  __shared__ float aggF[16][64];    // 4 KB: f32 agg rows for the tile
  __shared__ float sH[16][68];      // 4.25 KB: h round-trip (padded)
  int tile = blockIdx.x;
  int wv = threadIdx.x >> 6;        // wave 0..3
  int lane = threadIdx.x & 63;
  int r = lane >> 3, q = lane & 7;

  // ---- gather phase: wave wv handles nodes tile*16 + wv*4 .. +4 ----
  for (int k = 0; k < 4; ++k) {
    int node = tile * 16 + wv * 4 + k;

    float accA[8] = {0.f, 0.f, 0.f, 0.f, 0.f, 0.f, 0.f, 0.f};
    float accB[8] = {0.f, 0.f, 0.f, 0.f, 0.f, 0.f, 0.f, 0.f};

    int s0 = start[node], s1 = start[node + 1];
    for (int base = s0; base < s1; base += 64) {
      int cnt = s1 - base;
      if (cnt > 64) cnt = 64;
      int idxv = (lane < cnt) ? ssrc[base + lane] : 0;
      int j = 0;
      for (; j + 16 <= cnt; j += 16) {
        int iA = clampidx(__shfl(idxv, j + r));
        int iB = clampidx(__shfl(idxv, j + 8 + r));
        quadpk uA, uB;
        uA.v = xq[iA * 8 + q];
        uB.v = xq[iB * 8 + q];
#pragma unroll
        for (int t = 0; t < 8; ++t) {
          accA[t] += (float)uA.h[t];
          accB[t] += (float)uB.h[t];
        }
      }
      for (; j + 8 <= cnt; j += 8) {
        int iA = clampidx(__shfl(idxv, j + r));
        quadpk uA;
        uA.v = xq[iA * 8 + q];
#pragma unroll
        for (int t = 0; t < 8; ++t) accA[t] += (float)uA.h[t];
      }
      if (j < cnt) {
        int nrem = cnt - j;
        int iA = clampidx(__shfl(idxv, j + r));
        if (r < nrem) {
          quadpk uA;
          uA.v = xq[iA * 8 + q];
#pragma unroll
          for (int t = 0; t < 8; ++t) accA[t] += (float)uA.h[t];
        }
      }
    }
#pragma unroll
    for (int t = 0; t < 8; ++t) accA[t] += accB[t];
#pragma unroll
    for (int off = 8; off <= 32; off <<= 1) {
#pragma unroll
      for (int t = 0; t < 8; ++t) accA[t] += __shfl_xor(accA[t], off);
    }
    if (r == 0) {
      int nl = wv * 4 + k;
#pragma unroll
      for (int t = 0; t < 8; ++t) aggF[nl][q * 8 + t] = accA[t];
    }
  }
  __syncthreads();

  // ---- MLP phase: wave 0 only ----
  if (wv != 0) return;
  int m = lane & 15, quad = lane >> 4;

  half8 Aa[2], Ax[2];
#pragma unroll
  for (int s = 0; s < 2; ++s) {
    const float* pa = &aggF[m][s * 32 + quad * 8];
    half8 A;
#pragma unroll
    for (int jj = 0; jj < 8; ++jj) A[jj] = (_Float16)pa[jj];
    Aa[s] = A;
    Ax[s] = *(const half8*)(xh + (tile * 16 + m) * 64 + s * 32 + quad * 8);
  }

#pragma unroll
  for (int t = 0; t < 4; ++t) {
    int n = t * 16 + m;
    half8 Bl0 = *(const half8*)(wt1l + n * 32 + quad * 4);
    half8 Bl1 = *(const half8*)(wt1l + n * 32 + 16 + quad * 4);
    half8 Br0 = *(const half8*)(wt1r + n * 32 + quad * 4);
    half8 Br1 = *(const half8*)(wt1r + n * 32 + 16 + quad * 4);
    float4v acc = {0.f, 0.f, 0.f, 0.f};
    acc = __builtin_amdgcn_mfma_f32_16x16x32_f16(Aa[0], Bl0, acc, 0, 0, 0);
    acc = __builtin_amdgcn_mfma_f32_16x16x32_f16(Aa[1], Bl1, acc, 0, 0, 0);
    acc = __builtin_amdgcn_mfma_f32_16x16x32_f16(Ax[0], Br0, acc, 0, 0, 0);
    acc = __builtin_amdgcn_mfma_f32_16x16x32_f16(Ax[1], Br1, acc, 0, 0, 0);
    float bv = b1[n];
#pragma unroll
    for (int rr = 0; rr < 4; ++rr) {
      sH[quad * 4 + rr][n] = fmaxf(acc[rr] + bv, 0.f);
    }
  }

  half8 Ah[2];
#pragma unroll
  for (int s = 0; s < 2; ++s) {
    const float* pr = &sH[m][s * 32 + quad * 8];
    half8 A;
#pragma unroll
    for (int jj = 0; jj < 8; ++jj) A[jj] = (_Float16)pr[jj];
    Ah[s] = A;
  }

#pragma unroll
  for (int t = 0; t < 3; ++t) {
    int n = t * 16 + m;
    half8 Cl0 = *(const half8*)(wt2l + n * 32 + quad * 4);
    half8 Cl1 = *(const half8*)(wt2l + n * 32 + 16 + quad * 4);
    half8 Cr0 = *(const half8*)(wt2r + n * 32 + quad * 4);
    half8 Cr1 = *(const half8*)(wt2r + n * 32 + 16 + quad * 4);
    float4v acc2 = {0.f, 0.f, 0.f, 0.f};
    float4v acc3 = {0.f, 0.f, 0.f, 0.f};
    acc2 = __builtin_amdgcn_mfma_f32_16x16x32_f16(Ah[0], Cl0, acc2, 0, 0, 0);
    acc2 = __builtin_amdgcn_mfma_f32_16x16x32_f16(Ah[1], Cl1, acc2, 0, 0, 0);
    acc3 = __builtin_amdgcn_mfma_f32_16x16x32_f16(Ah[0], Cr0, acc3, 0, 0, 0);
    acc3 = __builtin_amdgcn_mfma_f32_16x16x32_f16(Ah[1], Cr1, acc3, 0, 0, 0);
    float bv = (n < N_CLASSES) ? b2[n] : 0.f;
#pragma unroll
    for (int rr = 0; rr < 4; ++rr) {
      int row = tile * 16 + quad * 4 + rr;
      hlh[row * NC48 + n] = (_Float16)acc2[rr];
      opart[row * NC48 + n] = acc3[rr] + bv;
    }
  }
}

// ---------------------------------------------------------------------------
// Gather 2 v3 (dwordx4) + softmax: hl rows = 6 quads (96 B).  Lanes with
// q<6 load; butterfly reduce; lanes (r==0, q<6) each own classes q*8..q*8+7.
// ---------------------------------------------------------------------------
__global__ __launch_bounds__(256) void gather2_kernel(
    const uint4* __restrict__ hq,          // hlh as quads [N][6]
    const float4* __restrict__ opart4,     // opart as float4 [N][12]
    const int* __restrict__ start, const int* __restrict__ ssrc,
    float* __restrict__ out) {
  int node = (blockIdx.x * 256 + threadIdx.x) >> 6;
  if (node >= N_NODES) return;
  int lane = threadIdx.x & 63;
  int r = lane >> 3, q = lane & 7;
  bool qOK = (q < 6);

  // own opart features (issued early)
  float op[8] = {0.f, 0.f, 0.f, 0.f, 0.f, 0.f, 0.f, 0.f};
  if (r == 0 && qOK) {
    float4 a = opart4[node * 12 + q * 2];
    float4 b = opart4[node * 12 + q * 2 + 1];
    op[0] = a.x; op[1] = a.y; op[2] = a.z; op[3] = a.w;
    op[4] = b.x; op[5] = b.y; op[6] = b.z; op[7] = b.w;
  }

  float accA[8] = {0.f, 0.f, 0.f, 0.f, 0.f, 0.f, 0.f, 0.f};
  float accB[8] = {0.f, 0.f, 0.f, 0.f, 0.f, 0.f, 0.f, 0.f};

  int s0 = start[node], s1 = start[node + 1];
  for (int base = s0; base < s1; base += 64) {
    int cnt = s1 - base;
    if (cnt > 64) cnt = 64;
    int idxv = (lane < cnt) ? ssrc[base + lane] : 0;
    int j = 0;
    for (; j + 16 <= cnt; j += 16) {
      int iA = clampidx(__shfl(idxv, j + r));
      int iB = clampidx(__shfl(idxv, j + 8 + r));
      if (qOK) {
        quadpk uA, uB;
        uA.v = hq[iA * 6 + q];
        uB.v = hq[iB * 6 + q];
#pragma unroll
        for (int t = 0; t < 8; ++t) {
          accA[t] += (float)uA.h[t];
          accB[t] += (float)uB.h[t];
        }
      }
    }
    for (; j + 8 <= cnt; j += 8) {
      int iA = clampidx(__shfl(idxv, j + r));
      if (qOK) {
        quadpk uA;
        uA.v = hq[iA * 6 + q];
#pragma unroll
        for (int t = 0; t < 8; ++t) accA[t] += (float)uA.h[t];
      }
    }
    if (j < cnt) {
      int nrem = cnt - j;
      int iA = clampidx(__shfl(idxv, j + r));
      if (r < nrem && qOK) {
        quadpk uA;
        uA.v = hq[iA * 6 + q];
#pragma unroll
        for (int t = 0; t < 8; ++t) accA[t] += (float)uA.h[t];
      }
    }
  }
#pragma unroll
  for (int t = 0; t < 8; ++t) accA[t] += accB[t];
#pragma unroll
  for (int off = 8; off <= 32; off <<= 1) {
#pragma unroll
    for (int t = 0; t < 8; ++t) accA[t] += __shfl_xor(accA[t], off);
  }

  // lanes (r==0, q<6): o[t] = opart + agg for class f = q*8+t (valid f<41)
  bool own = (r == 0) && qOK;
  float o[8];
  float lmax = -INFINITY;
#pragma unroll
  for (int t = 0; t < 8; ++t) {
    int f = q * 8 + t;
    o[t] = op[t] + accA[t];
    if (own && f < N_CLASSES) lmax = fmaxf(lmax, o[t]);
  }
  float vm = own ? lmax : -INFINITY;
#pragma unroll
  for (int off = 32; off >= 1; off >>= 1) vm = fmaxf(vm, __shfl_xor(vm, off));
  float lsum = 0.f;
#pragma unroll
  for (int t = 0; t < 8; ++t) {
    int f = q * 8 + t;
    if (own && f < N_CLASSES) lsum += expf(o[t] - vm);
  }
#pragma unroll
  for (int off = 32; off >= 1; off >>= 1) lsum += __shfl_xor(lsum, off);
  float lse = logf(lsum);
  if (own) {
#pragma unroll
    for (int t = 0; t < 8; ++t) {
      int f = q * 8 + t;
      if (f < N_CLASSES) out[node * N_CLASSES + f] = o[t] - vm - lse;
    }
  }
}

// ---------------------------------------------------------------------------
extern "C" void kernel_launch(void* const* d_in, const int* in_sizes, int n_in,
                              void* d_out, int out_size, void* d_ws, size_t ws_size,
                              hipStream_t stream) {
  const float* x   = (const float*)d_in[0];
  const float* W1l = (const float*)d_in[1];
  const float* W1r = (const float*)d_in[2];
  const float* b1  = (const float*)d_in[3];
  const float* W2l = (const float*)d_in[4];
  const float* W2r = (const float*)d_in[5];
  const float* b2  = (const float*)d_in[6];
  const int*   src = (const int*)d_in[7];
  const int*   dst = (const int*)d_in[8];
  float* out = (float*)d_out;

  // ---- byte-exact R0/R14 proven layout (ssrc at partial+64) ----
  int* counts  = (int*)d_ws;
  int* start   = counts + N_NODES;
  int* cursor  = start + (N_NODES + 1);
  int* partial = cursor + N_NODES;
  int* ssrc    = partial + 64;
  unsigned* wt1l = (unsigned*)(ssrc + N_EDGES);
  unsigned* wt1r = wt1l + 2048;
  unsigned* wt2l = wt1r + 2048;
  unsigned* wt2r = wt2l + 1536;
  // 256-B align opart so all downstream quad accesses are naturally aligned
  uintptr_t pal = ((uintptr_t)(wt2r + 1536) + 255) & ~(uintptr_t)255;
  float* opart   = (float*)pal;
  _Float16* xh   = (_Float16*)(opart + (size_t)N_NODES * NC48);
  _Float16* hlh  = xh + (size_t)N_NODES * 64;

  // pairs (12.8 MB) aliases opart (19.2 MB): fully consumed by sort2
  // before g1mlp produces opart.  wcur[500] lives in the 6.4 MB tail of the
  // same alias region (written by scanC, dead after bucketA) -> zero net
  // workspace growth vs the proven layout.
  int2* pairs = (int2*)opart;
  int*  wcur  = (int*)(pairs + N_EDGES);

  int eblocks = (N_EDGES + 255) / 256;   // 6250

  zeroc_kernel<<<(N_NODES + 255) / 256, 256, 0, stream>>>(counts);
  packx_kernel<<<(N_NODES * 64 + 255) / 256, 256, 0, stream>>>(x, xh);
  packwts_kernel<<<(7168 + 255) / 256, 256, 0, stream>>>(
      W1l, W1r, W2l, W2r, wt1l, wt1r, wt2l, wt2r);
  hist_kernel<<<eblocks, 256, 0, stream>>>(dst, counts);
  scanA_kernel<<<SCAN_NBLK, 256, 0, stream>>>(counts, partial);
  scanB_kernel<<<1, 64, 0, stream>>>(partial, start);
  scanC_kernel<<<SCAN_NBLK, 256, 0, stream>>>(counts, partial, start, cursor, wcur);
  bucketA_kernel<<<BA_BLOCKS, 256, 0, stream>>>(src, dst, wcur, pairs);
  sort2_kernel<<<NBUK, 256, 0, stream>>>(pairs, start, cursor, ssrc);

  g1mlp_kernel<<<N_TILES, 256, 0, stream>>>(
      (const uint4*)xh, start, ssrc, xh, wt1l, wt1r, wt2l, wt2r,
      b1, b2, hlh, opart);

  int gblocks = (N_NODES * 64 + 255) / 256;   // one wave per node
  gather2_kernel<<<gblocks, 256, 0, stream>>>(
      (const uint4*)hlh, (const float4*)opart, start, ssrc, out);
}

// Round 5
// 248.610 us; speedup vs baseline: 1.4929x; 1.2531x over previous
//
#include <hip/hip_runtime.h>
#include <hip/hip_bf16.h>
#include <math.h>

#define N_NODES   100000
#define N_EDGES   1600000
#define IN_FEAT   50
#define HIDDEN    64
#define N_CLASSES 41
#define NC48      48          // padded class width
#define N_TILES   (N_NODES / 16)   // 6250 exactly

// R15-18: bucketed counting sort
#define NPB   200                      // nodes per bucket
#define NBUK  (N_NODES / NPB)          // 500 buckets exactly
#define BEPT  16                       // edges per thread in bucketA/bhist
#define BA_BLOCKS ((N_EDGES + 256 * BEPT - 1) / (256 * BEPT))  // 391
#define SCAP  4096                     // sort2 LDS staging capacity (edges)

typedef __attribute__((ext_vector_type(8))) _Float16 half8;
typedef __attribute__((ext_vector_type(4))) float   float4v;

union f16pk { _Float16 h[2]; unsigned u; };
union quadpk { uint4 v; _Float16 h[8]; };

// index clamp: any value outside [0,N_NODES) becomes 0 (defensive; see R11)
__device__ __forceinline__ int clampidx(int i) {
  return ((unsigned)i < (unsigned)N_NODES) ? i : 0;
}

// f16 accumulate via v_fma_mix_f32: one VALU op per element instead of
// cvt+add.  `one` is a runtime kernel arg so InstCombine cannot fold
// fma(x,1.0,c)->fadd and break the mix pattern.  Numerically exact.
__device__ __forceinline__ void acc8(float* acc, const quadpk& u, float one) {
#pragma unroll
  for (int t = 0; t < 8; ++t) acc[t] = fmaf((float)u.h[t], one, acc[t]);
}

// ---------------------------------------------------------------------------
// Prep A: x (f32 [N][50]) -> xh (f16 [N][64], k-padded with zeros)
// ---------------------------------------------------------------------------
__global__ __launch_bounds__(256) void packx_kernel(
    const float* __restrict__ x, _Float16* __restrict__ xh) {
  int i = blockIdx.x * 256 + threadIdx.x;
  if (i >= N_NODES * 64) return;
  int node = i >> 6, c = i & 63;
  xh[i] = (c < IN_FEAT) ? (_Float16)x[node * IN_FEAT + c] : (_Float16)0.f;
}

// ---------------------------------------------------------------------------
// Prep B: pack transposed f16-pair weights for MFMA B-fragments.
// Block 0 additionally zeroes the 512-int bucket-count array (consumed by
// bhist, a later kernel -> ordering guaranteed by stream).
// ---------------------------------------------------------------------------
__global__ __launch_bounds__(256) void packwts_kernel(
    const float* __restrict__ W1l, const float* __restrict__ W1r,
    const float* __restrict__ W2l, const float* __restrict__ W2r,
    unsigned* __restrict__ wt1l, unsigned* __restrict__ wt1r,
    unsigned* __restrict__ wt2l, unsigned* __restrict__ wt2r,
    int* __restrict__ bcnt) {
  if (blockIdx.x == 0) {
    for (int j = threadIdx.x; j < 512; j += 256) bcnt[j] = 0;
  }
  int i = blockIdx.x * 256 + threadIdx.x;
  f16pk pk;
  if (i < 2048 * 2) {                       // layer-1 weights
    int which = i >> 11, j = i & 2047;
    int n = j >> 5, kp = j & 31;
    const float* W = which ? W1r : W1l;
    int k0 = 2 * kp, k1 = 2 * kp + 1;
    pk.h[0] = (_Float16)((k0 < IN_FEAT) ? W[k0 * HIDDEN + n] : 0.f);
    pk.h[1] = (_Float16)((k1 < IN_FEAT) ? W[k1 * HIDDEN + n] : 0.f);
    (which ? wt1r : wt1l)[j] = pk.u;
  } else if (i < 4096 + 2 * 1536) {         // layer-2 weights
    int j = i - 4096;
    int which = (j >= 1536), jj = which ? j - 1536 : j;
    int n = jj >> 5, kp = jj & 31;
    const float* W = which ? W2r : W2l;
    pk.h[0] = (_Float16)((n < N_CLASSES) ? W[(2 * kp) * N_CLASSES + n] : 0.f);
    pk.h[1] = (_Float16)((n < N_CLASSES) ? W[(2 * kp + 1) * N_CLASSES + n] : 0.f);
    (which ? wt2r : wt2l)[jj] = pk.u;
  }
}

// ---------------------------------------------------------------------------
// R18: bucket-granularity histogram (replaces the 1.6M-global-atomic
// per-node hist).  LDS-aggregated: 500 counters per block, then <=500
// global atomics per block.
// ---------------------------------------------------------------------------
__global__ __launch_bounds__(256) void bhist_kernel(
    const int* __restrict__ dst, int* __restrict__ bcnt) {
  __shared__ int lh[NBUK];
  int tid = threadIdx.x;
  for (int i = tid; i < NBUK; i += 256) lh[i] = 0;
  __syncthreads();
  int base = blockIdx.x * (256 * BEPT);
#pragma unroll
  for (int k = 0; k < BEPT; ++k) {
    int e = base + k * 256 + tid;
    if (e < N_EDGES) {
      int d = clampidx(dst[e]);
      atomicAdd(&lh[(unsigned)d / (unsigned)NPB], 1);
    }
  }
  __syncthreads();
  for (int i = tid; i < NBUK; i += 256)
    if (lh[i]) atomicAdd(&bcnt[i], lh[i]);
}

// ---------------------------------------------------------------------------
// R18: scan the 500 bucket counts -> wbase[0..500] (stable bases for sort2),
// wcur[] (atomically bumped by bucketA), start[N_NODES]=N_EDGES sentinel.
// 256 threads, 2 values each.
// ---------------------------------------------------------------------------
__global__ __launch_bounds__(256) void bscan_kernel(
    const int* __restrict__ bcnt, int* __restrict__ wbase,
    int* __restrict__ wcur, int* __restrict__ start) {
  __shared__ int lds[256];
  int tid = threadIdx.x;
  int i0 = 2 * tid, i1 = 2 * tid + 1;
  int a0 = (i0 < NBUK) ? bcnt[i0] : 0;
  int a1 = (i1 < NBUK) ? bcnt[i1] : 0;
  int s = a0 + a1;
  lds[tid] = s;
  __syncthreads();
  for (int off = 1; off < 256; off <<= 1) {         // Hillis-Steele inclusive
    int t = (tid >= off) ? lds[tid - off] : 0;
    __syncthreads();
    lds[tid] += t;
    __syncthreads();
  }
  int excl = lds[tid] - s;                          // exclusive over pairs
  if (i0 < NBUK) { wbase[i0] = excl;      wcur[i0] = excl; }
  if (i1 < NBUK) { wbase[i1] = excl + a0; wcur[i1] = excl + a0; }
  if (tid == 0) { wbase[NBUK] = N_EDGES; start[N_NODES] = N_EDGES; }
}

// ---------------------------------------------------------------------------
// R15 phase A (hardened): single pass over (src,dst); LDS-rank edges into 500
// buckets of NPB=200 nodes; regions pairs[wbase[b]..wbase[b+1]).
// Every scatter index is unsigned-clamped so no state corruption can fault.
// ---------------------------------------------------------------------------
__global__ __launch_bounds__(256) void bucketA_kernel(
    const int* __restrict__ src, const int* __restrict__ dst,
    int* __restrict__ wcur, int2* __restrict__ pairs) {
  __shared__ int lcnt[NBUK];
  __shared__ int lbase[NBUK];
  int tid = threadIdx.x;
  for (int i = tid; i < NBUK; i += 256) lcnt[i] = 0;
  __syncthreads();
  int base = blockIdx.x * (256 * BEPT);
  int s[BEPT], d[BEPT], rk[BEPT];
#pragma unroll
  for (int k = 0; k < BEPT; ++k) {
    int e = base + k * 256 + tid;
    rk[k] = -1;
    if (e < N_EDGES) {
      s[k] = src[e];
      d[k] = clampidx(dst[e]);
      int w = (unsigned)d[k] / (unsigned)NPB;       // < NBUK by construction
      rk[k] = atomicAdd(&lcnt[w], 1);
    }
  }
  __syncthreads();
  for (int i = tid; i < NBUK; i += 256)
    lbase[i] = atomicAdd(&wcur[i], lcnt[i]);
  __syncthreads();
#pragma unroll
  for (int k = 0; k < BEPT; ++k) {
    if (rk[k] >= 0) {
      int w = (unsigned)d[k] / (unsigned)NPB;
      int pos = lbase[w] + rk[k];
      if ((unsigned)pos < (unsigned)N_EDGES) {      // defensive: cannot fault
        int2 p; p.x = s[k]; p.y = d[k];
        pairs[pos] = p;
      }
    }
  }
}

// ---------------------------------------------------------------------------
// R18 sort2 v2: per-bucket LDS counting sort that also PRODUCES start[].
// Pass 1: LDS histogram of the bucket's 200 nodes over its ~3200 pairs.
// Parallel LDS scan -> per-node offsets; write start[] slice (coalesced).
// Pass 2: scatter src into 16KB LDS staging, stream out contiguously.
// All LDS/global scatter indices bounded.  Skew fallback (> SCAP edges)
// scatters globally via LDS cursors (bounded, correct, never taken for
// random dst: mean 3200, sigma ~56).
// ---------------------------------------------------------------------------
__global__ __launch_bounds__(256) void sort2_kernel(
    const int2* __restrict__ pairs, const int* __restrict__ wbase,
    int* __restrict__ start, int* __restrict__ ssrc) {
  __shared__ int obuf[SCAP];
  __shared__ int lhist[NPB];
  __shared__ int lcur[NPB];
  __shared__ int lscan[256];
  int b = blockIdx.x;
  int nbase = b * NPB;
  int lo = wbase[b];
  int hi = wbase[b + 1];
  int ne = hi - lo;
  int tid = threadIdx.x;
  for (int i = tid; i < NPB; i += 256) lhist[i] = 0;
  __syncthreads();
  // pass 1: in-bucket histogram
  for (int i = lo + tid; i < hi; i += 256) {
    int2 p = pairs[i];
    unsigned li = (unsigned)(p.y - nbase);
    if (li < (unsigned)NPB) atomicAdd(&lhist[li], 1);
  }
  __syncthreads();
  // parallel exclusive scan of the 200 counts (padded to 256)
  int hv = (tid < NPB) ? lhist[tid] : 0;
  lscan[tid] = hv;
  __syncthreads();
  for (int off = 1; off < 256; off <<= 1) {
    int t = (tid >= off) ? lscan[tid - off] : 0;
    __syncthreads();
    lscan[tid] += t;
    __syncthreads();
  }
  if (tid < NPB) {
    int excl = lscan[tid] - hv;
    lcur[tid] = excl;
    unsigned sidx = (unsigned)(nbase + tid);
    if (sidx < (unsigned)N_NODES) start[sidx] = lo + excl;  // coalesced slice
  }
  __syncthreads();
  // pass 2: scatter
  if (ne >= 0 && ne <= SCAP) {
    for (int i = lo + tid; i < hi; i += 256) {
      int2 p = pairs[i];
      unsigned li = (unsigned)(p.y - nbase);
      if (li < (unsigned)NPB) {
        int pos = atomicAdd(&lcur[li], 1);
        if ((unsigned)pos < (unsigned)SCAP) obuf[pos] = p.x;
      }
    }
    __syncthreads();
    for (int i = tid; i < ne; i += 256) {
      unsigned gi = (unsigned)(lo + i);
      if (gi < (unsigned)N_EDGES) ssrc[gi] = obuf[i];
    }
  } else {
    // skew fallback: global scatter via LDS cursors (bounded)
    for (int i = lo + tid; i < hi; i += 256) {
      int2 p = pairs[i];
      unsigned li = (unsigned)(p.y - nbase);
      if (li < (unsigned)NPB) {
        int pos = atomicAdd(&lcur[li], 1);
        unsigned gi = (unsigned)(lo + pos);
        if (gi < (unsigned)N_EDGES) ssrc[gi] = p.x;
      }
    }
  }
}

// ---------------------------------------------------------------------------
// Fused gather1 + MLP: one block per 16-node tile (6250 blocks).
// Waves 0-3 each gather 4 nodes -> agg rows in f32 LDS; wave 0 runs the
// MFMA MLP for the tile.  Gather accumulate uses v_fma_mix (acc8).
// ---------------------------------------------------------------------------
__global__ __launch_bounds__(256) void g1mlp_kernel(
    const uint4* __restrict__ xq,          // xh as quads [N][8]
    const int* __restrict__ start, const int* __restrict__ ssrc,
    const _Float16* __restrict__ xh,
    const unsigned* __restrict__ wt1l, const unsigned* __restrict__ wt1r,
    const unsigned* __restrict__ wt2l, const unsigned* __restrict__ wt2r,
    const float* __restrict__ b1, const float* __restrict__ b2,
    _Float16* __restrict__ hlh, float* __restrict__ opart, float one) {
  __shared__ float aggF[16][64];    // 4 KB: f32 agg rows for the tile
  __shared__ float sH[16][68];      // 4.25 KB: h round-trip (padded)
  int tile = blockIdx.x;
  int wv = threadIdx.x >> 6;        // wave 0..3
  int lane = threadIdx.x & 63;
  int r = lane >> 3, q = lane & 7;

  // ---- gather phase: wave wv handles nodes tile*16 + wv*4 .. +4 ----
  for (int k = 0; k < 4; ++k) {
    int node = tile * 16 + wv * 4 + k;

    float accA[8] = {0.f, 0.f, 0.f, 0.f, 0.f, 0.f, 0.f, 0.f};
    float accB[8] = {0.f, 0.f, 0.f, 0.f, 0.f, 0.f, 0.f, 0.f};

    int s0 = start[node], s1 = start[node + 1];
    for (int base = s0; base < s1; base += 64) {
      int cnt = s1 - base;
      if (cnt > 64) cnt = 64;
      int idxv = (lane < cnt) ? ssrc[base + lane] : 0;
      int j = 0;
      for (; j + 16 <= cnt; j += 16) {
        int iA = clampidx(__shfl(idxv, j + r));
        int iB = clampidx(__shfl(idxv, j + 8 + r));
        quadpk uA, uB;
        uA.v = xq[iA * 8 + q];
        uB.v = xq[iB * 8 + q];
        acc8(accA, uA, one);
        acc8(accB, uB, one);
      }
      for (; j + 8 <= cnt; j += 8) {
        int iA = clampidx(__shfl(idxv, j + r));
        quadpk uA;
        uA.v = xq[iA * 8 + q];
        acc8(accA, uA, one);
      }
      if (j < cnt) {
        int nrem = cnt - j;
        int iA = clampidx(__shfl(idxv, j + r));
        if (r < nrem) {
          quadpk uA;
          uA.v = xq[iA * 8 + q];
          acc8(accA, uA, one);
        }
      }
    }
#pragma unroll
    for (int t = 0; t < 8; ++t) accA[t] += accB[t];
#pragma unroll
    for (int off = 8; off <= 32; off <<= 1) {
#pragma unroll
      for (int t = 0; t < 8; ++t) accA[t] += __shfl_xor(accA[t], off);
    }
    if (r == 0) {
      int nl = wv * 4 + k;
#pragma unroll
      for (int t = 0; t < 8; ++t) aggF[nl][q * 8 + t] = accA[t];
    }
  }
  __syncthreads();

  // ---- MLP phase: wave 0 only ----
  if (wv != 0) return;
  int m = lane & 15, quad = lane >> 4;

  half8 Aa[2], Ax[2];
#pragma unroll
  for (int s = 0; s < 2; ++s) {
    const float* pa = &aggF[m][s * 32 + quad * 8];
    half8 A;
#pragma unroll
    for (int jj = 0; jj < 8; ++jj) A[jj] = (_Float16)pa[jj];
    Aa[s] = A;
    Ax[s] = *(const half8*)(xh + (tile * 16 + m) * 64 + s * 32 + quad * 8);
  }

#pragma unroll
  for (int t = 0; t < 4; ++t) {
    int n = t * 16 + m;
    half8 Bl0 = *(const half8*)(wt1l + n * 32 + quad * 4);
    half8 Bl1 = *(const half8*)(wt1l + n * 32 + 16 + quad * 4);
    half8 Br0 = *(const half8*)(wt1r + n * 32 + quad * 4);
    half8 Br1 = *(const half8*)(wt1r + n * 32 + 16 + quad * 4);
    float4v acc = {0.f, 0.f, 0.f, 0.f};
    acc = __builtin_amdgcn_mfma_f32_16x16x32_f16(Aa[0], Bl0, acc, 0, 0, 0);
    acc = __builtin_amdgcn_mfma_f32_16x16x32_f16(Aa[1], Bl1, acc, 0, 0, 0);
    acc = __builtin_amdgcn_mfma_f32_16x16x32_f16(Ax[0], Br0, acc, 0, 0, 0);
    acc = __builtin_amdgcn_mfma_f32_16x16x32_f16(Ax[1], Br1, acc, 0, 0, 0);
    float bv = b1[n];
#pragma unroll
    for (int rr = 0; rr < 4; ++rr) {
      sH[quad * 4 + rr][n] = fmaxf(acc[rr] + bv, 0.f);
    }
  }

  half8 Ah[2];
#pragma unroll
  for (int s = 0; s < 2; ++s) {
    const float* pr = &sH[m][s * 32 + quad * 8];
    half8 A;
#pragma unroll
    for (int jj = 0; jj < 8; ++jj) A[jj] = (_Float16)pr[jj];
    Ah[s] = A;
  }

#pragma unroll
  for (int t = 0; t < 3; ++t) {
    int n = t * 16 + m;
    half8 Cl0 = *(const half8*)(wt2l + n * 32 + quad * 4);
    half8 Cl1 = *(const half8*)(wt2l + n * 32 + 16 + quad * 4);
    half8 Cr0 = *(const half8*)(wt2r + n * 32 + quad * 4);
    half8 Cr1 = *(const half8*)(wt2r + n * 32 + 16 + quad * 4);
    float4v acc2 = {0.f, 0.f, 0.f, 0.f};
    float4v acc3 = {0.f, 0.f, 0.f, 0.f};
    acc2 = __builtin_amdgcn_mfma_f32_16x16x32_f16(Ah[0], Cl0, acc2, 0, 0, 0);
    acc2 = __builtin_amdgcn_mfma_f32_16x16x32_f16(Ah[1], Cl1, acc2, 0, 0, 0);
    acc3 = __builtin_amdgcn_mfma_f32_16x16x32_f16(Ah[0], Cr0, acc3, 0, 0, 0);
    acc3 = __builtin_amdgcn_mfma_f32_16x16x32_f16(Ah[1], Cr1, acc3, 0, 0, 0);
    float bv = (n < N_CLASSES) ? b2[n] : 0.f;
#pragma unroll
    for (int rr = 0; rr < 4; ++rr) {
      int row = tile * 16 + quad * 4 + rr;
      hlh[row * NC48 + n] = (_Float16)acc2[rr];
      opart[row * NC48 + n] = acc3[rr] + bv;
    }
  }
}

// ---------------------------------------------------------------------------
// Gather 2 + softmax.  Accumulate via v_fma_mix (acc8); softmax butterflies
// trimmed to 3 stages (owning lanes live in lanes 0..7 only).
// ---------------------------------------------------------------------------
__global__ __launch_bounds__(256) void gather2_kernel(
    const uint4* __restrict__ hq,          // hlh as quads [N][6]
    const float4* __restrict__ opart4,     // opart as float4 [N][12]
    const int* __restrict__ start, const int* __restrict__ ssrc,
    float* __restrict__ out, float one) {
  int node = (blockIdx.x * 256 + threadIdx.x) >> 6;
  if (node >= N_NODES) return;
  int lane = threadIdx.x & 63;
  int r = lane >> 3, q = lane & 7;
  bool qOK = (q < 6);

  // own opart features (issued early)
  float op[8] = {0.f, 0.f, 0.f, 0.f, 0.f, 0.f, 0.f, 0.f};
  if (r == 0 && qOK) {
    float4 a = opart4[node * 12 + q * 2];
    float4 b = opart4[node * 12 + q * 2 + 1];
    op[0] = a.x; op[1] = a.y; op[2] = a.z; op[3] = a.w;
    op[4] = b.x; op[5] = b.y; op[6] = b.z; op[7] = b.w;
  }

  float accA[8] = {0.f, 0.f, 0.f, 0.f, 0.f, 0.f, 0.f, 0.f};
  float accB[8] = {0.f, 0.f, 0.f, 0.f, 0.f, 0.f, 0.f, 0.f};

  int s0 = start[node], s1 = start[node + 1];
  for (int base = s0; base < s1; base += 64) {
    int cnt = s1 - base;
    if (cnt > 64) cnt = 64;
    int idxv = (lane < cnt) ? ssrc[base + lane] : 0;
    int j = 0;
    for (; j + 16 <= cnt; j += 16) {
      int iA = clampidx(__shfl(idxv, j + r));
      int iB = clampidx(__shfl(idxv, j + 8 + r));
      if (qOK) {
        quadpk uA, uB;
        uA.v = hq[iA * 6 + q];
        uB.v = hq[iB * 6 + q];
        acc8(accA, uA, one);
        acc8(accB, uB, one);
      }
    }
    for (; j + 8 <= cnt; j += 8) {
      int iA = clampidx(__shfl(idxv, j + r));
      if (qOK) {
        quadpk uA;
        uA.v = hq[iA * 6 + q];
        acc8(accA, uA, one);
      }
    }
    if (j < cnt) {
      int nrem = cnt - j;
      int iA = clampidx(__shfl(idxv, j + r));
      if (r < nrem && qOK) {
        quadpk uA;
        uA.v = hq[iA * 6 + q];
        acc8(accA, uA, one);
      }
    }
  }
#pragma unroll
  for (int t = 0; t < 8; ++t) accA[t] += accB[t];
#pragma unroll
  for (int off = 8; off <= 32; off <<= 1) {
#pragma unroll
    for (int t = 0; t < 8; ++t) accA[t] += __shfl_xor(accA[t], off);
  }

  // lanes (r==0, q<6): o[t] = opart + agg for class f = q*8+t (valid f<41)
  bool own = (r == 0) && qOK;
  float o[8];
  float lmax = -INFINITY;
#pragma unroll
  for (int t = 0; t < 8; ++t) {
    int f = q * 8 + t;
    o[t] = op[t] + accA[t];
    if (own && f < N_CLASSES) lmax = fmaxf(lmax, o[t]);
  }
  // owning lanes are 0..5: 3-stage butterfly within the 8-lane group suffices
  float vm = own ? lmax : -INFINITY;
#pragma unroll
  for (int off = 4; off >= 1; off >>= 1) vm = fmaxf(vm, __shfl_xor(vm, off));
  float lsum = 0.f;
#pragma unroll
  for (int t = 0; t < 8; ++t) {
    int f = q * 8 + t;
    if (own && f < N_CLASSES) lsum += expf(o[t] - vm);
  }
#pragma unroll
  for (int off = 4; off >= 1; off >>= 1) lsum += __shfl_xor(lsum, off);
  float lse = logf(lsum);
  if (own) {
#pragma unroll
    for (int t = 0; t < 8; ++t) {
      int f = q * 8 + t;
      if (f < N_CLASSES) out[node * N_CLASSES + f] = o[t] - vm - lse;
    }
  }
}

// ---------------------------------------------------------------------------
extern "C" void kernel_launch(void* const* d_in, const int* in_sizes, int n_in,
                              void* d_out, int out_size, void* d_ws, size_t ws_size,
                              hipStream_t stream) {
  const float* x   = (const float*)d_in[0];
  const float* W1l = (const float*)d_in[1];
  const float* W1r = (const float*)d_in[2];
  const float* b1  = (const float*)d_in[3];
  const float* W2l = (const float*)d_in[4];
  const float* W2r = (const float*)d_in[5];
  const float* b2  = (const float*)d_in[6];
  const int*   src = (const int*)d_in[7];
  const int*   dst = (const int*)d_in[8];
  float* out = (float*)d_out;

  // ---- byte-exact proven layout (ssrc at partial+64) ----
  int* counts  = (int*)d_ws;            // region now hosts bcnt/wbase only
  int* start   = counts + N_NODES;
  int* cursor  = start + (N_NODES + 1); // dead, reserved
  int* partial = cursor + N_NODES;      // dead, reserved
  int* ssrc    = partial + 64;
  unsigned* wt1l = (unsigned*)(ssrc + N_EDGES);
  unsigned* wt1r = wt1l + 2048;
  unsigned* wt2l = wt1r + 2048;
  unsigned* wt2r = wt2l + 1536;
  // 256-B align opart so all downstream quad accesses are naturally aligned
  uintptr_t pal = ((uintptr_t)(wt2r + 1536) + 255) & ~(uintptr_t)255;
  float* opart   = (float*)pal;
  _Float16* xh   = (_Float16*)(opart + (size_t)N_NODES * NC48);
  _Float16* hlh  = xh + (size_t)N_NODES * 64;

  // bcnt[512] + wbase[512] live in the (otherwise dead) counts region.
  int* bcnt  = counts;
  int* wbase = counts + 512;

  // pairs (12.8 MB) aliases opart (19.2 MB): fully consumed by sort2
  // before g1mlp produces opart.  wcur[500] in the alias-region tail.
  int2* pairs = (int2*)opart;
  int*  wcur  = (int*)(pairs + N_EDGES);

  packx_kernel<<<(N_NODES * 64 + 255) / 256, 256, 0, stream>>>(x, xh);
  packwts_kernel<<<(7168 + 255) / 256, 256, 0, stream>>>(
      W1l, W1r, W2l, W2r, wt1l, wt1r, wt2l, wt2r, bcnt);
  bhist_kernel<<<BA_BLOCKS, 256, 0, stream>>>(dst, bcnt);
  bscan_kernel<<<1, 256, 0, stream>>>(bcnt, wbase, wcur, start);
  bucketA_kernel<<<BA_BLOCKS, 256, 0, stream>>>(src, dst, wcur, pairs);
  sort2_kernel<<<NBUK, 256, 0, stream>>>(pairs, wbase, start, ssrc);

  g1mlp_kernel<<<N_TILES, 256, 0, stream>>>(
      (const uint4*)xh, start, ssrc, xh, wt1l, wt1r, wt2l, wt2r,
      b1, b2, hlh, opart, 1.0f);

  int gblocks = (N_NODES * 64 + 255) / 256;   // one wave per node
  gather2_kernel<<<gblocks, 256, 0, stream>>>(
      (const uint4*)hlh, (const float4*)opart, start, ssrc, out, 1.0f);
}